// Round 7
// baseline (462.024 us; speedup 1.0000x reference)
//
#include <hip/hip_runtime.h>
#include <hip/hip_bf16.h>

// 2-layer GIN, fused pull-aggregation + MLP per layer, bf16 neighbor gathers.
//   agg = f32(hb[n]) + sum f32(hb[src]);  h' = relu(agg @ W + b)
// Nodes are processed in degree-sorted order (perm) so each wave handles
// near-equal-degree nodes -> no intra-wave serial-loop imbalance.
// CSR build = deterministic radix partition (no hot global atomics).
// Requires n_nodes < 2^18. Here N=100000, E=1600000, D=64.

#define D 64
#define RPB 32         // nodes per fused block
#define CHSZ 8192      // edges per chunk (k1/k3)
#define NPBS 512       // nodes per super-bucket
#define SBSHIFT 9      // log2(NPBS)
#define MAXNBS 256     // static LDS cap on #super-buckets (n_nodes <= 131072)
#define MAXNCH 512     // static LDS cap on #chunks in k2c (n_edges <= 4.2M)
#define DBINS 256      // degree bins (deg clamped to 255)

typedef unsigned short ushort_t;

__device__ inline unsigned short f2bf(float f) {   // RNE round to bf16
    unsigned u = __float_as_uint(f);
    return (unsigned short)((u + 0x7fff + ((u >> 16) & 1)) >> 16);
}

// acc[0..7] += 8 bf16 unpacked from one uint4
__device__ inline void acc8(float* acc, uint4 v) {
    acc[0] += __uint_as_float(v.x << 16);
    acc[1] += __uint_as_float(v.x & 0xffff0000u);
    acc[2] += __uint_as_float(v.y << 16);
    acc[3] += __uint_as_float(v.y & 0xffff0000u);
    acc[4] += __uint_as_float(v.z << 16);
    acc[5] += __uint_as_float(v.z & 0xffff0000u);
    acc[6] += __uint_as_float(v.w << 16);
    acc[7] += __uint_as_float(v.w & 0xffff0000u);
}

// ---------------- CSR build ----------------

__global__ void zero_small(int* __restrict__ total, int* __restrict__ degcnt, int nbs) {
    int i = threadIdx.x;
    for (int j = i; j < nbs; j += 256) total[j] = 0;
    for (int j = i; j < DBINS; j += 256) degcnt[j] = 0;
}

// Per-chunk LDS histogram; also accumulates per-bucket totals (replaces k2a).
__global__ __launch_bounds__(256) void k1_hist(const int* __restrict__ dst,
                                               int* __restrict__ hist,
                                               int* __restrict__ total,
                                               int n_edges, int nch, int nbs) {
    __shared__ int lh[MAXNBS];
    for (int i = threadIdx.x; i < nbs; i += 256) lh[i] = 0;
    __syncthreads();
    int base = blockIdx.x * CHSZ;
    int lim = min(CHSZ, n_edges - base);
    for (int k = threadIdx.x; k < lim; k += 256)
        atomicAdd(&lh[dst[base + k] >> SBSHIFT], 1);
    __syncthreads();
    for (int i = threadIdx.x; i < nbs; i += 256) {
        int v = lh[i];
        hist[i * nch + blockIdx.x] = v;   // bucket-major
        if (v) atomicAdd(&total[i], v);
    }
}

// Single tiny WG: exclusive scan of nbs (<=256) totals -> sstart.
__global__ __launch_bounds__(256) void k2b_scan(const int* __restrict__ total,
                                                int* __restrict__ sstart,
                                                int nbs, int n_edges) {
    __shared__ int t[256];
    int tid = threadIdx.x;
    t[tid] = (tid < nbs) ? total[tid] : 0;
    __syncthreads();
    for (int off = 1; off < 256; off <<= 1) {
        int v = (tid >= off) ? t[tid - off] : 0;
        __syncthreads();
        t[tid] += v;
        __syncthreads();
    }
    if (tid < nbs) sstart[tid] = (tid == 0) ? 0 : t[tid - 1];
    if (tid == 0) sstart[nbs] = n_edges;
}

// One block per bucket: exclusive scan of its row (+ sstart[b]), in place.
__global__ __launch_bounds__(256) void k2c_rowscan(int* __restrict__ hist,
                                                   const int* __restrict__ sstart,
                                                   int nch, int nbs) {
    __shared__ int t[MAXNCH];
    int b = blockIdx.x;
    int tid = threadIdx.x;
    int* row = hist + (size_t)b * nch;
    int nround = (nch + 255) & ~255;
    for (int i = tid; i < nround; i += 256) t[i] = (i < nch) ? row[i] : 0;
    __syncthreads();
    for (int off = 1; off < nround; off <<= 1) {
        int v[MAXNCH / 256];
        for (int i = tid, j = 0; i < nround; i += 256, ++j)
            v[j] = (i >= off) ? t[i - off] : 0;
        __syncthreads();
        for (int i = tid, j = 0; i < nround; i += 256, ++j) t[i] += v[j];
        __syncthreads();
    }
    int base = sstart[b];
    for (int i = tid; i < nch; i += 256)
        row[i] = base + ((i == 0) ? 0 : t[i - 1]);
}

__global__ __launch_bounds__(256) void k3_scatter(const int* __restrict__ src,
                                                  const int* __restrict__ dst,
                                                  const int* __restrict__ hist,
                                                  unsigned* __restrict__ tmp,
                                                  int n_edges, int nch, int nbs) {
    __shared__ int lcur[MAXNBS];
    int c = blockIdx.x;
    for (int i = threadIdx.x; i < nbs; i += 256) lcur[i] = hist[i * nch + c];
    __syncthreads();
    int base = c * CHSZ;
    int lim = min(CHSZ, n_edges - base);
    for (int k = threadIdx.x; k < lim; k += 256) {
        int d = dst[base + k];
        int s = src[base + k];
        int pos = atomicAdd(&lcur[d >> SBSHIFT], 1);
        tmp[pos] = ((unsigned)(d & (NPBS - 1)) << 18) | (unsigned)s;
    }
}

// One WG per super-bucket: node counting sort in a WG-owned window.
// Also block-aggregates the degree histogram for the perm build.
__global__ __launch_bounds__(256) void k4_fine(const unsigned* __restrict__ tmp,
                                               const int* __restrict__ sstart,
                                               int* __restrict__ esrc,
                                               int* __restrict__ offs,
                                               int* __restrict__ degcnt,
                                               int n_nodes) {
    __shared__ int lcnt[NPBS];
    __shared__ int lcur[NPBS];
    __shared__ int tsum[256];
    __shared__ int dcnt[DBINS];

    int b = blockIdx.x;
    int tid = threadIdx.x;
    int base = sstart[b];
    int cnt = sstart[b + 1] - base;

    lcnt[tid] = 0; lcnt[tid + 256] = 0;
    dcnt[tid] = 0;
    __syncthreads();

    for (int i = tid; i < cnt; i += 256)
        atomicAdd(&lcnt[tmp[base + i] >> 18], 1);
    __syncthreads();

    int a0 = lcnt[2 * tid], a1 = lcnt[2 * tid + 1];
    int node = b * NPBS + 2 * tid;
    if (node < n_nodes)     atomicAdd(&dcnt[min(a0, DBINS - 1)], 1);
    if (node + 1 < n_nodes) atomicAdd(&dcnt[min(a1, DBINS - 1)], 1);
    tsum[tid] = a0 + a1;
    __syncthreads();
    for (int off = 1; off < 256; off <<= 1) {
        int v = (tid >= off) ? tsum[tid - off] : 0;
        __syncthreads();
        tsum[tid] += v;
        __syncthreads();
    }
    int ex = (tid == 0) ? 0 : tsum[tid - 1];
    lcur[2 * tid] = ex;
    lcur[2 * tid + 1] = ex + a0;

    if (node <= n_nodes) offs[node] = base + ex;
    if (node + 1 <= n_nodes) offs[node + 1] = base + ex + a0;
    __syncthreads();

    if (dcnt[tid]) atomicAdd(&degcnt[tid], dcnt[tid]);   // ~30 nonzero bins/block

    for (int i = tid; i < cnt; i += 256) {
        unsigned p = tmp[base + i];
        int pos = atomicAdd(&lcur[p >> 18], 1);
        esrc[base + pos] = (int)(p & 0x3FFFFu);
    }
}

// Exclusive scan of the 256 degree-bin counts -> degcur (cursor bases).
__global__ __launch_bounds__(256) void degscan(const int* __restrict__ degcnt,
                                               int* __restrict__ degcur) {
    __shared__ int t[DBINS];
    int tid = threadIdx.x;
    t[tid] = degcnt[tid];
    __syncthreads();
    for (int off = 1; off < 256; off <<= 1) {
        int v = (tid >= off) ? t[tid - off] : 0;
        __syncthreads();
        t[tid] += v;
        __syncthreads();
    }
    degcur[tid] = (tid == 0) ? 0 : t[tid - 1];
}

// Block-aggregated scatter of nodes into degree-sorted perm (avoids hot
// same-address global atomics: one range-reservation per bin per block).
__global__ __launch_bounds__(256) void degscatter(const int* __restrict__ offs,
                                                  int* __restrict__ degcur,
                                                  int* __restrict__ perm,
                                                  int n_nodes) {
    __shared__ int lcnt[DBINS];
    __shared__ int lbase[DBINS];
    int tid = threadIdx.x;
    int n = blockIdx.x * 256 + tid;
    lcnt[tid] = 0;
    __syncthreads();
    int bin = -1, lpos = 0;
    if (n < n_nodes) {
        bin = min(offs[n + 1] - offs[n], DBINS - 1);
        lpos = atomicAdd(&lcnt[bin], 1);
    }
    __syncthreads();
    if (lcnt[tid]) lbase[tid] = atomicAdd(&degcur[tid], lcnt[tid]);
    __syncthreads();
    if (n < n_nodes) perm[lbase[bin] + lpos] = n;
}

// ---------------- per-layer kernels ----------------

// fp32 -> bf16 matrix conversion (RNE). n4 = count of float4.
__global__ __launch_bounds__(256) void to_bf16(const float4* __restrict__ in,
                                               uint2* __restrict__ out, int n4) {
    int i = blockIdx.x * 256 + threadIdx.x;
    if (i >= n4) return;
    float4 v = in[i];
    out[i] = make_uint2((unsigned)f2bf(v.x) | ((unsigned)f2bf(v.y) << 16),
                        (unsigned)f2bf(v.z) | ((unsigned)f2bf(v.w) << 16));
}

// Fused layer: block handles 32 nodes (perm order).
// Phase 1 (agg): 8 lanes/node, lane owns 8 bf16 cols (1 uint4/edge), fp32 acc,
//                self-term init (eps=0); result -> LDS rows.
// Phase 2 (mlp): 4 waves x 8 rows, lane = out col; relu; store to perm'd row.
template <bool BF16OUT>
__global__ __launch_bounds__(256) void gin_layer(const uint4* __restrict__ hb,
                                                 const int* __restrict__ offs,
                                                 const int* __restrict__ esrc,
                                                 const int* __restrict__ perm,
                                                 const float* __restrict__ W,
                                                 const float* __restrict__ bias,
                                                 void* __restrict__ out_,
                                                 int n_nodes) {
    __shared__ float Wl[D * D];       // 16 KiB
    __shared__ float bl[D];
    __shared__ float rows[RPB][D];    // 8 KiB
    __shared__ int pn[RPB];

    int tid = threadIdx.x;

    const float4* W4 = (const float4*)W;
    float4* Wl4 = (float4*)Wl;
#pragma unroll
    for (int i = 0; i < 4; ++i) Wl4[tid + 256 * i] = W4[tid + 256 * i];
    if (tid < D / 4) ((float4*)bl)[tid] = ((const float4*)bias)[tid];
    if (tid < RPB) {
        int r = blockIdx.x * RPB + tid;
        pn[tid] = (r < n_nodes) ? perm[r] : -1;
    }
    __syncthreads();

    // ---- phase 1: aggregation ----
    int g = tid >> 3;      // node slot 0..31
    int l = tid & 7;       // column chunk (8 bf16 = 1 uint4)
    int n = pn[g];
    float acc[8];
#pragma unroll
    for (int j = 0; j < 8; ++j) acc[j] = 0.0f;
    if (n >= 0) {
        acc8(acc, hb[(size_t)n * 8 + l]);   // self term
        int i = offs[n];
        int end = offs[n + 1];
        for (; i + 4 <= end; i += 4) {
            uint4 v0 = hb[(size_t)esrc[i]     * 8 + l];
            uint4 v1 = hb[(size_t)esrc[i + 1] * 8 + l];
            uint4 v2 = hb[(size_t)esrc[i + 2] * 8 + l];
            uint4 v3 = hb[(size_t)esrc[i + 3] * 8 + l];
            acc8(acc, v0); acc8(acc, v1); acc8(acc, v2); acc8(acc, v3);
        }
        for (; i < end; ++i)
            acc8(acc, hb[(size_t)esrc[i] * 8 + l]);
    }
#pragma unroll
    for (int j = 0; j < 8; ++j) rows[g][l * 8 + j] = acc[j];
    __syncthreads();

    // ---- phase 2: MLP ----
    int lane = tid & 63;
    int w = tid >> 6;

    float macc[8];
#pragma unroll
    for (int r = 0; r < 8; ++r) macc[r] = bl[lane];

#pragma unroll
    for (int k = 0; k < D; ++k) {
        float wv = Wl[k * D + lane];
#pragma unroll
        for (int r = 0; r < 8; ++r)
            macc[r] = fmaf(rows[w * 8 + r][k], wv, macc[r]);
    }

#pragma unroll
    for (int r = 0; r < 8; ++r) {
        int nr = pn[w * 8 + r];
        if (nr < 0) continue;
        float v = macc[r] > 0.0f ? macc[r] : 0.0f;
        size_t idx = (size_t)nr * D + lane;
        if (BF16OUT) ((ushort_t*)out_)[idx] = f2bf(v);
        else         ((float*)out_)[idx] = v;
    }
}

extern "C" void kernel_launch(void* const* d_in, const int* in_sizes, int n_in,
                              void* d_out, int out_size, void* d_ws, size_t ws_size,
                              hipStream_t stream) {
    const float* x   = (const float*)d_in[0];
    const int*   src = (const int*)d_in[1];
    const int*   dst = (const int*)d_in[2];
    const float* W1  = (const float*)d_in[3];
    const float* b1  = (const float*)d_in[4];
    const float* W2  = (const float*)d_in[5];
    const float* b2  = (const float*)d_in[6];
    float* out = (float*)d_out;

    const int n_nodes = in_sizes[0] / D;
    const int n_edges = in_sizes[1];
    const int nch = (n_edges + CHSZ - 1) / CHSZ;     // 196
    const int nbs = (n_nodes + NPBS - 1) / NPBS;     // 196

    // workspace: xb | h1b | offs | sstart | total | degcnt | degcur | hist |
    //            perm | tmp | esrc   (~40 MB)
    ushort_t* xb     = (ushort_t*)d_ws;                       // n_nodes*64 bf16
    ushort_t* h1b    = xb + (size_t)n_nodes * D;              // n_nodes*64 bf16
    int*      offs   = (int*)(h1b + (size_t)n_nodes * D);     // n_nodes+1
    int*      sstart = offs + (n_nodes + 1);                  // nbs+1
    int*      total  = sstart + (nbs + 1);                    // nbs
    int*      degcnt = total + nbs;                           // DBINS
    int*      degcur = degcnt + DBINS;                        // DBINS
    int*      hist   = degcur + DBINS;                        // nbs*nch
    int*      perm   = hist + (size_t)nbs * nch;              // n_nodes
    unsigned* tmp    = (unsigned*)(perm + n_nodes);           // n_edges
    int*      esrc   = (int*)(tmp + n_edges);                 // n_edges

    const int layer_blocks = (n_nodes + RPB - 1) / RPB;       // 3125
    const int cvt_blocks = (n_nodes * (D / 4) + 255) / 256;
    const int nscat_blocks = (n_nodes + 255) / 256;

    // ---- CSR build + degree-sorted perm (deterministic output) ----
    zero_small<<<1, 256, 0, stream>>>(total, degcnt, nbs);
    k1_hist<<<nch, 256, 0, stream>>>(dst, hist, total, n_edges, nch, nbs);
    k2b_scan<<<1, 256, 0, stream>>>(total, sstart, nbs, n_edges);
    k2c_rowscan<<<nbs, 256, 0, stream>>>(hist, sstart, nch, nbs);
    k3_scatter<<<nch, 256, 0, stream>>>(src, dst, hist, tmp, n_edges, nch, nbs);
    k4_fine<<<nbs, 256, 0, stream>>>(tmp, sstart, esrc, offs, degcnt, n_nodes);
    degscan<<<1, 256, 0, stream>>>(degcnt, degcur);
    degscatter<<<nscat_blocks, 256, 0, stream>>>(offs, degcur, perm, n_nodes);

    // ---- layer 1: xb = bf16(x); fused agg+mlp -> h1b (bf16) ----
    to_bf16<<<cvt_blocks, 256, 0, stream>>>((const float4*)x, (uint2*)xb,
                                            n_nodes * (D / 4));
    gin_layer<true><<<layer_blocks, 256, 0, stream>>>((const uint4*)xb, offs, esrc,
                                                      perm, W1, b1, h1b, n_nodes);

    // ---- layer 2: fused agg+mlp -> out (fp32) ----
    gin_layer<false><<<layer_blocks, 256, 0, stream>>>((const uint4*)h1b, offs, esrc,
                                                       perm, W2, b2, out, n_nodes);
}

// Round 8
// 217.475 us; speedup vs baseline: 2.1245x; 2.1245x over previous
//
#include <hip/hip_runtime.h>
#include <hip/hip_bf16.h>

// 2-layer GIN, pull-mode aggregation with bf16 neighbor gathers.
//   agg = f32(hb[n]) + sum f32(hb[src]);  h' = relu(agg @ W + b)
// gin_agg processes nodes in degree-sorted order (perm) so each wave's 16
// nodes have near-equal degree -> no serial-loop imbalance. Separate agg/mlp
// kernels (fusion in R7 spilled to 256 VGPR / 10% occupancy: reverted).
// CSR build = deterministic radix partition. n_nodes < 2^18.

#define D 64
#define ROWS_PER_BLOCK 32
#define CHSZ 8192      // edges per chunk (k1/k3)
#define NPBS 512       // nodes per super-bucket
#define SBSHIFT 9      // log2(NPBS)
#define MAXNBS 256     // static LDS cap on #super-buckets (n_nodes <= 131072)
#define MAXNCH 512     // static LDS cap on #chunks in k2c (n_edges <= 4.2M)
#define DBINS 256      // degree bins (deg clamped to 255)

typedef unsigned short ushort_t;

__device__ inline unsigned short f2bf(float f) {   // RNE round to bf16
    unsigned u = __float_as_uint(f);
    return (unsigned short)((u + 0x7fff + ((u >> 16) & 1)) >> 16);
}

// acc[0..7] += 8 bf16 unpacked from one uint4
__device__ inline void acc8(float* acc, uint4 v) {
    acc[0] += __uint_as_float(v.x << 16);
    acc[1] += __uint_as_float(v.x & 0xffff0000u);
    acc[2] += __uint_as_float(v.y << 16);
    acc[3] += __uint_as_float(v.y & 0xffff0000u);
    acc[4] += __uint_as_float(v.z << 16);
    acc[5] += __uint_as_float(v.z & 0xffff0000u);
    acc[6] += __uint_as_float(v.w << 16);
    acc[7] += __uint_as_float(v.w & 0xffff0000u);
}

// ---------------- CSR build ----------------

__global__ void zero_small(int* __restrict__ total, int* __restrict__ degcnt, int nbs) {
    int i = threadIdx.x;
    for (int j = i; j < nbs; j += 256) total[j] = 0;
    for (int j = i; j < DBINS; j += 256) degcnt[j] = 0;
}

// Per-chunk LDS histogram; also accumulates per-bucket totals.
__global__ __launch_bounds__(256) void k1_hist(const int* __restrict__ dst,
                                               int* __restrict__ hist,
                                               int* __restrict__ total,
                                               int n_edges, int nch, int nbs) {
    __shared__ int lh[MAXNBS];
    for (int i = threadIdx.x; i < nbs; i += 256) lh[i] = 0;
    __syncthreads();
    int base = blockIdx.x * CHSZ;
    int lim = min(CHSZ, n_edges - base);
    for (int k = threadIdx.x; k < lim; k += 256)
        atomicAdd(&lh[dst[base + k] >> SBSHIFT], 1);
    __syncthreads();
    for (int i = threadIdx.x; i < nbs; i += 256) {
        int v = lh[i];
        hist[i * nch + blockIdx.x] = v;   // bucket-major
        if (v) atomicAdd(&total[i], v);
    }
}

__global__ __launch_bounds__(256) void k2b_scan(const int* __restrict__ total,
                                                int* __restrict__ sstart,
                                                int nbs, int n_edges) {
    __shared__ int t[256];
    int tid = threadIdx.x;
    t[tid] = (tid < nbs) ? total[tid] : 0;
    __syncthreads();
    for (int off = 1; off < 256; off <<= 1) {
        int v = (tid >= off) ? t[tid - off] : 0;
        __syncthreads();
        t[tid] += v;
        __syncthreads();
    }
    if (tid < nbs) sstart[tid] = (tid == 0) ? 0 : t[tid - 1];
    if (tid == 0) sstart[nbs] = n_edges;
}

__global__ __launch_bounds__(256) void k2c_rowscan(int* __restrict__ hist,
                                                   const int* __restrict__ sstart,
                                                   int nch, int nbs) {
    __shared__ int t[MAXNCH];
    int b = blockIdx.x;
    int tid = threadIdx.x;
    int* row = hist + (size_t)b * nch;
    int nround = (nch + 255) & ~255;
    for (int i = tid; i < nround; i += 256) t[i] = (i < nch) ? row[i] : 0;
    __syncthreads();
    for (int off = 1; off < nround; off <<= 1) {
        int v[MAXNCH / 256];
        for (int i = tid, j = 0; i < nround; i += 256, ++j)
            v[j] = (i >= off) ? t[i - off] : 0;
        __syncthreads();
        for (int i = tid, j = 0; i < nround; i += 256, ++j) t[i] += v[j];
        __syncthreads();
    }
    int base = sstart[b];
    for (int i = tid; i < nch; i += 256)
        row[i] = base + ((i == 0) ? 0 : t[i - 1]);
}

__global__ __launch_bounds__(256) void k3_scatter(const int* __restrict__ src,
                                                  const int* __restrict__ dst,
                                                  const int* __restrict__ hist,
                                                  unsigned* __restrict__ tmp,
                                                  int n_edges, int nch, int nbs) {
    __shared__ int lcur[MAXNBS];
    int c = blockIdx.x;
    for (int i = threadIdx.x; i < nbs; i += 256) lcur[i] = hist[i * nch + c];
    __syncthreads();
    int base = c * CHSZ;
    int lim = min(CHSZ, n_edges - base);
    for (int k = threadIdx.x; k < lim; k += 256) {
        int d = dst[base + k];
        int s = src[base + k];
        int pos = atomicAdd(&lcur[d >> SBSHIFT], 1);
        tmp[pos] = ((unsigned)(d & (NPBS - 1)) << 18) | (unsigned)s;
    }
}

// One WG per super-bucket: node counting sort; block-aggregated degree hist.
__global__ __launch_bounds__(256) void k4_fine(const unsigned* __restrict__ tmp,
                                               const int* __restrict__ sstart,
                                               int* __restrict__ esrc,
                                               int* __restrict__ offs,
                                               int* __restrict__ degcnt,
                                               int n_nodes) {
    __shared__ int lcnt[NPBS];
    __shared__ int lcur[NPBS];
    __shared__ int tsum[256];
    __shared__ int dcnt[DBINS];

    int b = blockIdx.x;
    int tid = threadIdx.x;
    int base = sstart[b];
    int cnt = sstart[b + 1] - base;

    lcnt[tid] = 0; lcnt[tid + 256] = 0;
    dcnt[tid] = 0;
    __syncthreads();

    for (int i = tid; i < cnt; i += 256)
        atomicAdd(&lcnt[tmp[base + i] >> 18], 1);
    __syncthreads();

    int a0 = lcnt[2 * tid], a1 = lcnt[2 * tid + 1];
    int node = b * NPBS + 2 * tid;
    if (node < n_nodes)     atomicAdd(&dcnt[min(a0, DBINS - 1)], 1);
    if (node + 1 < n_nodes) atomicAdd(&dcnt[min(a1, DBINS - 1)], 1);
    tsum[tid] = a0 + a1;
    __syncthreads();
    for (int off = 1; off < 256; off <<= 1) {
        int v = (tid >= off) ? tsum[tid - off] : 0;
        __syncthreads();
        tsum[tid] += v;
        __syncthreads();
    }
    int ex = (tid == 0) ? 0 : tsum[tid - 1];
    lcur[2 * tid] = ex;
    lcur[2 * tid + 1] = ex + a0;

    if (node <= n_nodes) offs[node] = base + ex;
    if (node + 1 <= n_nodes) offs[node + 1] = base + ex + a0;
    __syncthreads();

    if (dcnt[tid]) atomicAdd(&degcnt[tid], dcnt[tid]);

    for (int i = tid; i < cnt; i += 256) {
        unsigned p = tmp[base + i];
        int pos = atomicAdd(&lcur[p >> 18], 1);
        esrc[base + pos] = (int)(p & 0x3FFFFu);
    }
}

__global__ __launch_bounds__(256) void degscan(const int* __restrict__ degcnt,
                                               int* __restrict__ degcur) {
    __shared__ int t[DBINS];
    int tid = threadIdx.x;
    t[tid] = degcnt[tid];
    __syncthreads();
    for (int off = 1; off < 256; off <<= 1) {
        int v = (tid >= off) ? t[tid - off] : 0;
        __syncthreads();
        t[tid] += v;
        __syncthreads();
    }
    degcur[tid] = (tid == 0) ? 0 : t[tid - 1];
}

// Block-aggregated scatter of nodes into degree-sorted perm.
__global__ __launch_bounds__(256) void degscatter(const int* __restrict__ offs,
                                                  int* __restrict__ degcur,
                                                  int* __restrict__ perm,
                                                  int n_nodes) {
    __shared__ int lcnt[DBINS];
    __shared__ int lbase[DBINS];
    int tid = threadIdx.x;
    int n = blockIdx.x * 256 + tid;
    lcnt[tid] = 0;
    __syncthreads();
    int bin = -1, lpos = 0;
    if (n < n_nodes) {
        bin = min(offs[n + 1] - offs[n], DBINS - 1);
        lpos = atomicAdd(&lcnt[bin], 1);
    }
    __syncthreads();
    if (lcnt[tid]) lbase[tid] = atomicAdd(&degcur[tid], lcnt[tid]);
    __syncthreads();
    if (n < n_nodes) perm[lbase[bin] + lpos] = n;
}

// ---------------- per-layer kernels ----------------

__global__ __launch_bounds__(256) void to_bf16(const float4* __restrict__ in,
                                               uint2* __restrict__ out, int n4) {
    int i = blockIdx.x * 256 + threadIdx.x;
    if (i >= n4) return;
    float4 v = in[i];
    out[i] = make_uint2((unsigned)f2bf(v.x) | ((unsigned)f2bf(v.y) << 16),
                        (unsigned)f2bf(v.z) | ((unsigned)f2bf(v.w) << 16));
}

// Pull aggregation over bf16 matrix: 4 lanes/node, node chosen via perm so a
// wave's 16 nodes have near-equal degree. Writes fp32 agg row A[n] (256B).
__global__ __launch_bounds__(256) void gin_agg_bf(const uint4* __restrict__ hb,
                                                  const int* __restrict__ offs,
                                                  const int* __restrict__ esrc,
                                                  const int* __restrict__ perm,
                                                  float4* __restrict__ agg,
                                                  int n_nodes) {
    int t = blockIdx.x * 256 + threadIdx.x;
    int nidx = t >> 2;
    if (nidx >= n_nodes) return;
    int n = perm[nidx];
    int c = t & 3;
    const uint4* self = hb + (size_t)n * 8 + c * 2;   // row = 8 uint4 (128 B)
    float acc[16];
#pragma unroll
    for (int j = 0; j < 16; ++j) acc[j] = 0.0f;
    uint4 sv0 = self[0], sv1 = self[1];
    acc8(acc, sv0); acc8(acc + 8, sv1);

    int i = offs[n];
    int end = offs[n + 1];
    for (; i + 4 <= end; i += 4) {
        const uint4* r0 = hb + (size_t)esrc[i]     * 8 + c * 2;
        const uint4* r1 = hb + (size_t)esrc[i + 1] * 8 + c * 2;
        const uint4* r2 = hb + (size_t)esrc[i + 2] * 8 + c * 2;
        const uint4* r3 = hb + (size_t)esrc[i + 3] * 8 + c * 2;
        uint4 a0 = r0[0], b0 = r0[1];
        uint4 a1 = r1[0], b1 = r1[1];
        uint4 a2 = r2[0], b2 = r2[1];
        uint4 a3 = r3[0], b3 = r3[1];
        acc8(acc, a0); acc8(acc + 8, b0);
        acc8(acc, a1); acc8(acc + 8, b1);
        acc8(acc, a2); acc8(acc + 8, b2);
        acc8(acc, a3); acc8(acc + 8, b3);
    }
    for (; i < end; ++i) {
        const uint4* r = hb + (size_t)esrc[i] * 8 + c * 2;
        uint4 a = r[0], b = r[1];
        acc8(acc, a); acc8(acc + 8, b);
    }

    float4* o = agg + (size_t)n * 16 + c * 4;
    o[0] = make_float4(acc[0], acc[1], acc[2], acc[3]);
    o[1] = make_float4(acc[4], acc[5], acc[6], acc[7]);
    o[2] = make_float4(acc[8], acc[9], acc[10], acc[11]);
    o[3] = make_float4(acc[12], acc[13], acc[14], acc[15]);
}

// out = relu(hs @ W + b); BF16OUT selects bf16 or fp32 output.
template <bool BF16OUT>
__global__ __launch_bounds__(256) void gin_mlp(const float* __restrict__ hs,
                                               const float* __restrict__ W,
                                               const float* __restrict__ b,
                                               void* __restrict__ out_,
                                               int n_nodes) {
    __shared__ float Wl[D * D];
    __shared__ float bl[D];
    __shared__ float rows[ROWS_PER_BLOCK][D];

    int tid = threadIdx.x;

    const float4* W4 = (const float4*)W;
    float4* Wl4 = (float4*)Wl;
#pragma unroll
    for (int i = 0; i < 4; ++i) Wl4[tid + 256 * i] = W4[tid + 256 * i];
    if (tid < D / 4) ((float4*)bl)[tid] = ((const float4*)b)[tid];

    size_t row0 = (size_t)blockIdx.x * ROWS_PER_BLOCK;
    const float4* hs4 = (const float4*)(hs + row0 * D);
    float4* rows4 = (float4*)rows;
#pragma unroll
    for (int i = 0; i < 2; ++i) rows4[tid + 256 * i] = hs4[tid + 256 * i];

    __syncthreads();

    int lane = tid & 63;
    int w = tid >> 6;

    float acc[8];
#pragma unroll
    for (int r = 0; r < 8; ++r) acc[r] = bl[lane];

#pragma unroll
    for (int k = 0; k < D; ++k) {
        float wv = Wl[k * D + lane];
#pragma unroll
        for (int r = 0; r < 8; ++r)
            acc[r] = fmaf(rows[w * 8 + r][k], wv, acc[r]);
    }

#pragma unroll
    for (int r = 0; r < 8; ++r) {
        float v = acc[r] > 0.0f ? acc[r] : 0.0f;
        size_t idx = (row0 + (size_t)w * 8 + r) * D + lane;
        if (BF16OUT) ((ushort_t*)out_)[idx] = f2bf(v);
        else         ((float*)out_)[idx] = v;
    }
}

extern "C" void kernel_launch(void* const* d_in, const int* in_sizes, int n_in,
                              void* d_out, int out_size, void* d_ws, size_t ws_size,
                              hipStream_t stream) {
    const float* x   = (const float*)d_in[0];
    const int*   src = (const int*)d_in[1];
    const int*   dst = (const int*)d_in[2];
    const float* W1  = (const float*)d_in[3];
    const float* b1  = (const float*)d_in[4];
    const float* W2  = (const float*)d_in[5];
    const float* b2  = (const float*)d_in[6];
    float* out = (float*)d_out;

    const int n_nodes = in_sizes[0] / D;
    const int n_edges = in_sizes[1];
    const int nch = (n_edges + CHSZ - 1) / CHSZ;     // 196
    const int nbs = (n_nodes + NPBS - 1) / NPBS;     // 196

    // workspace: A(f32) | hb(bf16) | offs | sstart | total | degcnt | degcur |
    //            hist | perm | tmp | esrc
    float*    A      = (float*)d_ws;                          // n_nodes*64 f32
    ushort_t* hb     = (ushort_t*)(A + (size_t)n_nodes * D);  // n_nodes*64 bf16
    int*      offs   = (int*)(hb + (size_t)n_nodes * D);      // n_nodes+1
    int*      sstart = offs + (n_nodes + 1);                  // nbs+1
    int*      total  = sstart + (nbs + 1);                    // nbs
    int*      degcnt = total + nbs;                           // DBINS
    int*      degcur = degcnt + DBINS;                        // DBINS
    int*      hist   = degcur + DBINS;                        // nbs*nch
    int*      perm   = hist + (size_t)nbs * nch;              // n_nodes
    unsigned* tmp    = (unsigned*)(perm + n_nodes);           // n_edges
    int*      esrc   = (int*)(tmp + n_edges);                 // n_edges

    const int agg_blocks = (n_nodes * 4 + 255) / 256;
    const int mlp_blocks = (n_nodes + ROWS_PER_BLOCK - 1) / ROWS_PER_BLOCK;
    const int cvt_blocks = (n_nodes * (D / 4) + 255) / 256;
    const int nscat_blocks = (n_nodes + 255) / 256;

    // ---- CSR build + degree-sorted perm ----
    zero_small<<<1, 256, 0, stream>>>(total, degcnt, nbs);
    k1_hist<<<nch, 256, 0, stream>>>(dst, hist, total, n_edges, nch, nbs);
    k2b_scan<<<1, 256, 0, stream>>>(total, sstart, nbs, n_edges);
    k2c_rowscan<<<nbs, 256, 0, stream>>>(hist, sstart, nch, nbs);
    k3_scatter<<<nch, 256, 0, stream>>>(src, dst, hist, tmp, n_edges, nch, nbs);
    k4_fine<<<nbs, 256, 0, stream>>>(tmp, sstart, esrc, offs, degcnt, n_nodes);
    degscan<<<1, 256, 0, stream>>>(degcnt, degcur);
    degscatter<<<nscat_blocks, 256, 0, stream>>>(offs, degcur, perm, n_nodes);

    // ---- layer 1: xb = bf16(x); agg -> A; mlp -> hb (bf16 h1) ----
    to_bf16<<<cvt_blocks, 256, 0, stream>>>((const float4*)x, (uint2*)hb,
                                            n_nodes * (D / 4));
    gin_agg_bf<<<agg_blocks, 256, 0, stream>>>((const uint4*)hb, offs, esrc,
                                               perm, (float4*)A, n_nodes);
    gin_mlp<true><<<mlp_blocks, 256, 0, stream>>>(A, W1, b1, hb, n_nodes);

    // ---- layer 2: agg(h1b) -> A; mlp -> out (fp32) ----
    gin_agg_bf<<<agg_blocks, 256, 0, stream>>>((const uint4*)hb, offs, esrc,
                                               perm, (float4*)A, n_nodes);
    gin_mlp<false><<<mlp_blocks, 256, 0, stream>>>(A, W2, b2, out, n_nodes);
}